// Round 7
// baseline (162.466 us; speedup 1.0000x reference)
//
#include <hip/hip_runtime.h>
#include <stdint.h>

#define NN 16384
#define MM 16384
#define DD 8
#define DV 16
#define WAVES 4
#define MT 2                        // 16-row m-tiles per wave
#define ROWS_WAVE (MT * 16)         // 32
#define ROWS_BLK (WAVES * ROWS_WAVE)// 128
#define JSPLIT 16
#define JCHUNK (MM / JSPLIT)        // 1024
#define J32 (JCHUNK / 32)           // 32 iterations per block

typedef short bf8 __attribute__((ext_vector_type(8)));   // 8 bf16 (4 VGPR)
typedef float f32x4 __attribute__((ext_vector_type(4))); // MFMA C/D

#define C3SQ 10.406844905028037f     /* 5*log2(e)^2 : folded into tables */
#define C2S  (1.2909944487358056f / 10.406844905028037f)  /* c2/c3sq */
#define LN2  0.6931471805599453f
// 2^{-f} Taylor coeffs, f in [-1/2, 1/2]:  sum (-ln2 f)^n / n!
#define EP1 (-0.6931471805599453f)
#define EP2 ( 0.2402265069591007f)
#define EP3 (-0.05550410866482158f)
#define EP4 ( 0.009618129107628477f)

__device__ __forceinline__ unsigned short f2bf(float f) {
    union { float f; uint32_t u; } c; c.f = f;
    uint32_t u = c.u + 0x7FFF + ((c.u >> 16) & 1);       // RNE
    return (unsigned short)(u >> 16);
}
__device__ __forceinline__ float bf2f(unsigned short h) {
    union { float f; uint32_t u; } c; c.u = ((uint32_t)h) << 16;
    return c.f;
}

#define BF16_ONE ((short)0x3F80)

// Matern transform: z = c3sq*d2 (from MFMA), k = (1 + LN2*t + C2S*z)*2^-t,
// t = sqrt(|z|).
// R18: exp2 (trans unit, ~19.5cy occupancy) replaced by FULL-RATE sequence:
//   i = rndne(t); f = t - i (f in [-.5,.5]); p = deg-4 Taylor of 2^-f
//   (err <= 4e-6, far under bf16 rounding); k = ldexp(pm*p, -i).
// rndne+sub+cvt(neg)+4fma+mul+ldexp = 8 full-rate (16cy) < exp2 (~19.5cy);
// the old pm*e mul is absorbed into the merged ldexp. sqrt stays on trans
// (no full-rate substitute beats it).
__device__ __forceinline__ float ktrans(float z) {
    float a = __builtin_fabsf(z);               // folds as |src| modifier
    float t = __builtin_amdgcn_sqrtf(a);        // trans
    float i = __builtin_rintf(t);               // v_rndne_f32
    float f = t - i;                            // f in [-0.5, 0.5]
    int   n = (int)(-i);                        // v_cvt_i32_f32 w/ neg mod
    float p = fmaf(f, fmaf(f, fmaf(f, fmaf(f, EP4, EP3), EP2), EP1), 1.f);
    float pm = fmaf(C2S, a, fmaf(LN2, t, 1.f));
    return __builtin_ldexpf(p * pm, n);         // v_ldexp_f32
}

// Pack two f32 -> one dword of 2 bf16 (lo=k0, hi=k1).
// Plain __bf16 casts: clang fuses the pair into ONE v_cvt_pk_bf16_f32.
__device__ __forceinline__ unsigned int pk2(float k0, float k1) {
    typedef __bf16 bf2v __attribute__((ext_vector_type(2)));
    union { bf2v v; unsigned int u; } cv;
    cv.v[0] = (__bf16)k0;
    cv.v[1] = (__bf16)k1;
    return cv.u;
}

// Tables with the SCALED d2 fold: MFMA emits z = c3sq*d2 directly.
//   quads 0..2 of B hold w = -2*c3sq*y (split hi,hi,lo AFTER fp32 scaling)
//   quad 3: A {1,1,csx_hi,csx_lo} x B {csy_hi,csy_lo,1,1}, c* = c3sq-scaled
// btbl K-order: slot k=8q+i -> j = 4q + (i&3) + (i>=4 ? 16 : 0), matching
// the REGISTER layout of the swapped first MFMA's C/D (lane holds m=n,
// j = quad*4+s per tile) so the transformed values ARE the A-fragment.
__global__ __launch_bounds__(256) void prep_frags(const float* __restrict__ ls,
                                                  const float* __restrict__ y,
                                                  const float* __restrict__ b,
                                                  bf8* __restrict__ ytbl,
                                                  bf8* __restrict__ btbl,
                                                  float4* __restrict__ outz) {
    const int tile = blockIdx.x * 4 + (threadIdx.x >> 6);  // 0..1023 (j16 tiles)
    const int lane = threadIdx.x & 63;
    const int n = lane & 15, quad = lane >> 4;

    // zero d_out: 256 blocks * 256 threads * 16B = 1 MB
    outz[blockIdx.x * 256 + threadIdx.x] = make_float4(0.f, 0.f, 0.f, 0.f);

    float lsv[DD];
#pragma unroll
    for (int d = 0; d < DD; ++d) lsv[d] = ls[d];

    const float4* yr4 = (const float4*)(y + (size_t)(tile * 16 + n) * DD);
    float4 ya = yr4[0], yb = yr4[1];
    float yv[DD] = {ya.x, ya.y, ya.z, ya.w, yb.x, yb.y, yb.z, yb.w};

    float syv = 0.f;
    unsigned short wh[DD], wl[DD];
#pragma unroll
    for (int d = 0; d < DD; ++d) {
        syv = fmaf(lsv[d] * yv[d], yv[d], syv);
        float w = -2.f * C3SQ * yv[d];          // scale in fp32, THEN split
        wh[d] = f2bf(w);
        wl[d] = f2bf(w - bf2f(wh[d]));
    }

    bf8 fr;
    if (quad < 3) {
#pragma unroll
        for (int d = 0; d < DD; ++d)
            fr[d] = (short)((quad == 2) ? wl[d] : wh[d]);
    } else {
        float csy = C3SQ * syv;
        unsigned short sh = f2bf(csy);
        unsigned short sl = f2bf(csy - bf2f(sh));
        fr[0] = (short)sh;      // k=24: 1 * csy_hi
        fr[1] = (short)sl;      // k=25: 1 * csy_lo
        fr[2] = BF16_ONE;       // k=26: csx_hi * 1
        fr[3] = BF16_ONE;       // k=27: csx_lo * 1
        fr[4] = 0; fr[5] = 0; fr[6] = 0; fr[7] = 0;
    }
    ytbl[tile * 64 + lane] = fr;

    if (tile < MM / 32) {             // j32 tiles for phase B, register K-order
        bf8 bfr;
#pragma unroll
        for (int s = 0; s < 8; ++s) {
            int k = quad * 8 + s;
            int q = k >> 3, r = k & 7;
            int jl = q * 4 + (r & 3) + ((r & 4) ? 16 : 0);
            float bv = b[(size_t)(tile * 32 + jl) * DV + n];
            bfr[s] = (short)f2bf(bv);
        }
        btbl[tile * 64 + lane] = bfr;
    }
}

// R18 = R17 (zero-LDS operand-swap, proven 81.9us) + exp2 -> full-rate
// ldexp+poly (see ktrans). Per element-vector: 2 trans + 3 full (45cy)
// -> 1 trans + 10 full (39.5cy). Model-discriminating: if the 30% gap was
// trans-pipe drain, dur drops ~11%; if real idle, dur is flat.
__global__ __launch_bounds__(256, 8) void matern_mfma(const float* __restrict__ ls,
                                                      const float* __restrict__ x,
                                                      const bf8* __restrict__ ytbl,
                                                      const bf8* __restrict__ btbl,
                                                      float* __restrict__ out) {
    const int t = threadIdx.x;
    const int lane = t & 63, wave = t >> 6;
    const int n = lane & 15, quad = lane >> 4;
    const int waverow = blockIdx.x * ROWS_BLK + wave * ROWS_WAVE;

    float lsv[DD];
#pragma unroll
    for (int d = 0; d < DD; ++d) lsv[d] = ls[d];

    // A-frags (used as B operand now; same lane layout: lane&15 = x-row):
    // quad 0/2 -> xls_hi, quad 1 -> xls_lo, quad 3 -> {1,1,csx_hi,csx_lo}
    bf8 afrag[MT];
#pragma unroll
    for (int mt = 0; mt < MT; ++mt) {
        const float* xr = x + (size_t)(waverow + mt * 16 + n) * DD;
        float sx = 0.f;
        unsigned short xh[DD], xl[DD];
#pragma unroll
        for (int d = 0; d < DD; ++d) {
            float xv = xr[d];
            float xlsv = lsv[d] * xv;
            sx = fmaf(xlsv, xv, sx);
            xh[d] = f2bf(xlsv);
            xl[d] = f2bf(xlsv - bf2f(xh[d]));
        }
        bf8 fr;
        if (quad == 3) {
            float csx = C3SQ * sx;               // scale in fp32, THEN split
            unsigned short sh = f2bf(csx);
            unsigned short sl = f2bf(csx - bf2f(sh));
            fr[0] = BF16_ONE;   // k=24: 1 * csy_hi
            fr[1] = BF16_ONE;   // k=25: 1 * csy_lo
            fr[2] = (short)sh;  // k=26: csx_hi * 1
            fr[3] = (short)sl;  // k=27: csx_lo * 1
            fr[4] = 0; fr[5] = 0; fr[6] = 0; fr[7] = 0;
        } else {
#pragma unroll
            for (int d = 0; d < DD; ++d)
                fr[d] = (short)((quad == 1) ? xl[d] : xh[d]);
        }
        afrag[mt] = fr;
    }

    f32x4 acc[MT];
#pragma unroll
    for (int mt = 0; mt < MT; ++mt) acc[mt] = (f32x4){0.f, 0.f, 0.f, 0.f};

    const int tile16base = blockIdx.y * (JCHUNK / 16);
    const int tile32base = blockIdx.y * (JCHUNK / 32);

    const f32x4 z4 = (f32x4){0.f, 0.f, 0.f, 0.f};   // loop-invariant C=0

    // prologue loads for it=0
    bf8 yA = ytbl[(size_t)(tile16base) * 64 + lane];
    bf8 yB = ytbl[(size_t)(tile16base + 1) * 64 + lane];
    bf8 bb = btbl[(size_t)(tile32base) * 64 + lane];

#pragma unroll 2
    for (int it = 0; it < J32; ++it) {
        // prefetch it+1 (wrap keeps the dead last prefetch in-chunk/in-bounds)
        const int nx = (it + 1) & (J32 - 1);
        bf8 nyA = ytbl[(size_t)(tile16base + nx * 2) * 64 + lane];
        bf8 nyB = ytbl[(size_t)(tile16base + nx * 2 + 1) * 64 + lane];
        bf8 nbb = btbl[(size_t)(tile32base + nx) * 64 + lane];

#pragma unroll
        for (int mt = 0; mt < MT; ++mt) {
            // SWAPPED operands: D = z^T, lane (n,quad) holds
            // z[j = quad*4+s][m = n] for each 16-wide j-tile.
            f32x4 s0 = __builtin_amdgcn_mfma_f32_16x16x32_bf16(yA, afrag[mt], z4, 0, 0, 0);
            f32x4 s1 = __builtin_amdgcn_mfma_f32_16x16x32_bf16(yB, afrag[mt], z4, 0, 0, 0);
            // Transform in registers; pack as the next MFMA's A-fragment:
            // slot k=8*quad+i -> j = 4*quad+(i&3) + (i>=4)*16  (btbl matches)
            union { bf8 v; unsigned int u[4]; } pa;
            pa.u[0] = pk2(ktrans(s0[0]), ktrans(s0[1]));
            pa.u[1] = pk2(ktrans(s0[2]), ktrans(s0[3]));
            pa.u[2] = pk2(ktrans(s1[0]), ktrans(s1[1]));
            pa.u[3] = pk2(ktrans(s1[2]), ktrans(s1[3]));
            acc[mt] = __builtin_amdgcn_mfma_f32_16x16x32_bf16(pa.v, bb, acc[mt], 0, 0, 0);
        }
        yA = nyA; yB = nyB; bb = nbb;
    }

    // Epilogue: D layout row=quad*4+s (=m), col=n (=v); JSPLIT partials via atomics
#pragma unroll
    for (int mt = 0; mt < MT; ++mt)
#pragma unroll
        for (int s = 0; s < 4; ++s) {
            const int row = waverow + mt * 16 + quad * 4 + s;
            atomicAdd(out + (size_t)row * DV + n, acc[mt][s]);
        }
}

extern "C" void kernel_launch(void* const* d_in, const int* in_sizes, int n_in,
                              void* d_out, int out_size, void* d_ws, size_t ws_size,
                              hipStream_t stream) {
    const float* ls = (const float*)d_in[0];
    const float* x  = (const float*)d_in[1];
    const float* y  = (const float*)d_in[2];
    const float* b  = (const float*)d_in[3];
    float* out = (float*)d_out;

    char* ws = (char*)d_ws;
    bf8* ytbl = (bf8*)ws;                        // 1024*64*16B = 1 MB
    bf8* btbl = (bf8*)(ws + (1 << 20));          // 512*64*16B  = 512 KB

    prep_frags<<<MM / 64, 256, 0, stream>>>(ls, y, b, ytbl, btbl, (float4*)out);
    matern_mfma<<<dim3(NN / ROWS_BLK, JSPLIT), 256, 0, stream>>>(ls, x, ytbl, btbl, out);
}

// Round 8
// 130.069 us; speedup vs baseline: 1.2491x; 1.2491x over previous
//
#include <hip/hip_runtime.h>
#include <stdint.h>

#define NN 16384
#define MM 16384
#define DD 8
#define DV 16
#define WAVES 4
#define MT 2                        // 16-row m-tiles per wave
#define ROWS_WAVE (MT * 16)         // 32
#define ROWS_BLK (WAVES * ROWS_WAVE)// 128
#define JSPLIT 32
#define JCHUNK (MM / JSPLIT)        // 512
#define J32 (JCHUNK / 32)           // 16 iterations per block

typedef short bf8 __attribute__((ext_vector_type(8)));   // 8 bf16 (4 VGPR)
typedef float f32x4 __attribute__((ext_vector_type(4))); // MFMA C/D

#define C3SQ 10.406844905028037f     /* 5*log2(e)^2 : folded into tables */
#define C2S  (1.2909944487358056f / 10.406844905028037f)  /* c2/c3sq */
#define LN2  0.6931471805599453f

__device__ __forceinline__ unsigned short f2bf(float f) {
    union { float f; uint32_t u; } c; c.f = f;
    uint32_t u = c.u + 0x7FFF + ((c.u >> 16) & 1);       // RNE
    return (unsigned short)(u >> 16);
}
__device__ __forceinline__ float bf2f(unsigned short h) {
    union { float f; uint32_t u; } c; c.u = ((uint32_t)h) << 16;
    return c.f;
}

#define BF16_ONE ((short)0x3F80)

// Matern transform: z = c3sq*d2 (from MFMA), k = (1 + LN2*t + C2S*z)*2^-t,
// t = sqrt(|z|). fabs folds into sqrt's |src|; -t folds into exp2's neg.
// R18 POST-MORTEM: trans ops issue at ~2.4cy/wave64 on gfx950 (two-equation
// solve across R17/R18) — sqrt+exp2 are CHEAP; the poly substitute cost
// +46%. This 5-op form is the minimum-instruction transform. Keep it.
__device__ __forceinline__ float ktrans(float z) {
    float a = __builtin_fabsf(z);
    float t = __builtin_amdgcn_sqrtf(a);
    float e = __builtin_amdgcn_exp2f(-t);
    return fmaf(C2S, a, fmaf(LN2, t, 1.f)) * e;
}

// Pack two f32 -> one dword of 2 bf16 (lo=k0, hi=k1).
// Plain __bf16 casts: clang fuses the pair into ONE v_cvt_pk_bf16_f32.
__device__ __forceinline__ unsigned int pk2(float k0, float k1) {
    typedef __bf16 bf2v __attribute__((ext_vector_type(2)));
    union { bf2v v; unsigned int u; } cv;
    cv.v[0] = (__bf16)k0;
    cv.v[1] = (__bf16)k1;
    return cv.u;
}

// Tables with the SCALED d2 fold: MFMA emits z = c3sq*d2 directly.
//   quads 0..2 of B hold w = -2*c3sq*y (split hi,hi,lo AFTER fp32 scaling)
//   quad 3: A {1,1,csx_hi,csx_lo} x B {csy_hi,csy_lo,1,1}, c* = c3sq-scaled
// btbl K-order: slot k=8q+i -> j = 4q + (i&3) + (i>=4 ? 16 : 0), matching
// the REGISTER layout of the swapped first MFMA's C/D (lane holds m=n,
// j = quad*4+s per tile) so the transformed values ARE the A-fragment.
__global__ __launch_bounds__(256) void prep_frags(const float* __restrict__ ls,
                                                  const float* __restrict__ y,
                                                  const float* __restrict__ b,
                                                  bf8* __restrict__ ytbl,
                                                  bf8* __restrict__ btbl,
                                                  float4* __restrict__ outz) {
    const int tile = blockIdx.x * 4 + (threadIdx.x >> 6);  // 0..1023 (j16 tiles)
    const int lane = threadIdx.x & 63;
    const int n = lane & 15, quad = lane >> 4;

    // zero d_out: 256 blocks * 256 threads * 16B = 1 MB
    outz[blockIdx.x * 256 + threadIdx.x] = make_float4(0.f, 0.f, 0.f, 0.f);

    float lsv[DD];
#pragma unroll
    for (int d = 0; d < DD; ++d) lsv[d] = ls[d];

    const float4* yr4 = (const float4*)(y + (size_t)(tile * 16 + n) * DD);
    float4 ya = yr4[0], yb = yr4[1];
    float yv[DD] = {ya.x, ya.y, ya.z, ya.w, yb.x, yb.y, yb.z, yb.w};

    float syv = 0.f;
    unsigned short wh[DD], wl[DD];
#pragma unroll
    for (int d = 0; d < DD; ++d) {
        syv = fmaf(lsv[d] * yv[d], yv[d], syv);
        float w = -2.f * C3SQ * yv[d];          // scale in fp32, THEN split
        wh[d] = f2bf(w);
        wl[d] = f2bf(w - bf2f(wh[d]));
    }

    bf8 fr;
    if (quad < 3) {
#pragma unroll
        for (int d = 0; d < DD; ++d)
            fr[d] = (short)((quad == 2) ? wl[d] : wh[d]);
    } else {
        float csy = C3SQ * syv;
        unsigned short sh = f2bf(csy);
        unsigned short sl = f2bf(csy - bf2f(sh));
        fr[0] = (short)sh;      // k=24: 1 * csy_hi
        fr[1] = (short)sl;      // k=25: 1 * csy_lo
        fr[2] = BF16_ONE;       // k=26: csx_hi * 1
        fr[3] = BF16_ONE;       // k=27: csx_lo * 1
        fr[4] = 0; fr[5] = 0; fr[6] = 0; fr[7] = 0;
    }
    ytbl[tile * 64 + lane] = fr;

    if (tile < MM / 32) {             // j32 tiles for phase B, register K-order
        bf8 bfr;
#pragma unroll
        for (int s = 0; s < 8; ++s) {
            int k = quad * 8 + s;
            int q = k >> 3, r = k & 7;
            int jl = q * 4 + (r & 3) + ((r & 4) ? 16 : 0);
            float bv = b[(size_t)(tile * 32 + jl) * DV + n];
            bfr[s] = (short)f2bf(bv);
        }
        btbl[tile * 64 + lane] = bfr;
    }
}

// R19 = R17 structure (zero-LDS operand-swap, proven 81.9us; R18 poly
// REVERTED — trans ops are ~2.4cy, poly cost +46%) + two stall fixes:
//  - z-MFMA hoist: all 4 z-MFMAs (both mt) issue before any transform,
//    so mt=1's MFMA latency (~30-40cy) hides under mt=0's ~55-instr
//    transform. Targets the 30% VALU non-busy gap.
//  - JSPLIT 16->32 (4096 blocks, 16/CU): occupancy backfill. Every
//    4096+-block config measured 64-67% occupancy vs 52% at 2048.
// Attribution: hoist -> VALUBusy up; JSPLIT -> Occupancy up + WRITE 32MB.
__global__ __launch_bounds__(256, 8) void matern_mfma(const float* __restrict__ ls,
                                                      const float* __restrict__ x,
                                                      const bf8* __restrict__ ytbl,
                                                      const bf8* __restrict__ btbl,
                                                      float* __restrict__ out) {
    const int t = threadIdx.x;
    const int lane = t & 63, wave = t >> 6;
    const int n = lane & 15, quad = lane >> 4;
    const int waverow = blockIdx.x * ROWS_BLK + wave * ROWS_WAVE;

    float lsv[DD];
#pragma unroll
    for (int d = 0; d < DD; ++d) lsv[d] = ls[d];

    // A-frags (used as B operand; lane&15 = x-row):
    // quad 0/2 -> xls_hi, quad 1 -> xls_lo, quad 3 -> {1,1,csx_hi,csx_lo}
    bf8 afrag[MT];
#pragma unroll
    for (int mt = 0; mt < MT; ++mt) {
        const float* xr = x + (size_t)(waverow + mt * 16 + n) * DD;
        float sx = 0.f;
        unsigned short xh[DD], xl[DD];
#pragma unroll
        for (int d = 0; d < DD; ++d) {
            float xv = xr[d];
            float xlsv = lsv[d] * xv;
            sx = fmaf(xlsv, xv, sx);
            xh[d] = f2bf(xlsv);
            xl[d] = f2bf(xlsv - bf2f(xh[d]));
        }
        bf8 fr;
        if (quad == 3) {
            float csx = C3SQ * sx;               // scale in fp32, THEN split
            unsigned short sh = f2bf(csx);
            unsigned short sl = f2bf(csx - bf2f(sh));
            fr[0] = BF16_ONE;   // k=24: 1 * csy_hi
            fr[1] = BF16_ONE;   // k=25: 1 * csy_lo
            fr[2] = (short)sh;  // k=26: csx_hi * 1
            fr[3] = (short)sl;  // k=27: csx_lo * 1
            fr[4] = 0; fr[5] = 0; fr[6] = 0; fr[7] = 0;
        } else {
#pragma unroll
            for (int d = 0; d < DD; ++d)
                fr[d] = (short)((quad == 1) ? xl[d] : xh[d]);
        }
        afrag[mt] = fr;
    }

    f32x4 acc[MT];
#pragma unroll
    for (int mt = 0; mt < MT; ++mt) acc[mt] = (f32x4){0.f, 0.f, 0.f, 0.f};

    const int tile16base = blockIdx.y * (JCHUNK / 16);
    const int tile32base = blockIdx.y * (JCHUNK / 32);

    const f32x4 z4 = (f32x4){0.f, 0.f, 0.f, 0.f};   // loop-invariant C=0

    // prologue loads for it=0
    bf8 yA = ytbl[(size_t)(tile16base) * 64 + lane];
    bf8 yB = ytbl[(size_t)(tile16base + 1) * 64 + lane];
    bf8 bb = btbl[(size_t)(tile32base) * 64 + lane];

#pragma unroll 2
    for (int it = 0; it < J32; ++it) {
        // prefetch it+1 (wrap keeps the dead last prefetch in-chunk/in-bounds)
        const int nx = (it + 1) & (J32 - 1);
        bf8 nyA = ytbl[(size_t)(tile16base + nx * 2) * 64 + lane];
        bf8 nyB = ytbl[(size_t)(tile16base + nx * 2 + 1) * 64 + lane];
        bf8 nbb = btbl[(size_t)(tile32base + nx) * 64 + lane];

        // Issue ALL z-MFMAs up front (4 in flight); the transform of the
        // first pair covers the latency of the second pair.
        // SWAPPED operands: D = z^T, lane (n,quad) holds z[j=quad*4+s][m=n].
        f32x4 s0a = __builtin_amdgcn_mfma_f32_16x16x32_bf16(yA, afrag[0], z4, 0, 0, 0);
        f32x4 s1a = __builtin_amdgcn_mfma_f32_16x16x32_bf16(yB, afrag[0], z4, 0, 0, 0);
        f32x4 s0b = __builtin_amdgcn_mfma_f32_16x16x32_bf16(yA, afrag[1], z4, 0, 0, 0);
        f32x4 s1b = __builtin_amdgcn_mfma_f32_16x16x32_bf16(yB, afrag[1], z4, 0, 0, 0);

        // Transform in registers; pack as the next MFMA's A-fragment:
        // slot k=8*quad+i -> j = 4*quad+(i&3) + (i>=4)*16  (btbl matches)
        union { bf8 v; unsigned int u[4]; } pa0, pa1;
        pa0.u[0] = pk2(ktrans(s0a[0]), ktrans(s0a[1]));
        pa0.u[1] = pk2(ktrans(s0a[2]), ktrans(s0a[3]));
        pa0.u[2] = pk2(ktrans(s1a[0]), ktrans(s1a[1]));
        pa0.u[3] = pk2(ktrans(s1a[2]), ktrans(s1a[3]));
        acc[0] = __builtin_amdgcn_mfma_f32_16x16x32_bf16(pa0.v, bb, acc[0], 0, 0, 0);

        pa1.u[0] = pk2(ktrans(s0b[0]), ktrans(s0b[1]));
        pa1.u[1] = pk2(ktrans(s0b[2]), ktrans(s0b[3]));
        pa1.u[2] = pk2(ktrans(s1b[0]), ktrans(s1b[1]));
        pa1.u[3] = pk2(ktrans(s1b[2]), ktrans(s1b[3]));
        acc[1] = __builtin_amdgcn_mfma_f32_16x16x32_bf16(pa1.v, bb, acc[1], 0, 0, 0);

        yA = nyA; yB = nyB; bb = nbb;
    }

    // Epilogue: D layout row=quad*4+s (=m), col=n (=v); JSPLIT partials via atomics
#pragma unroll
    for (int mt = 0; mt < MT; ++mt)
#pragma unroll
        for (int s = 0; s < 4; ++s) {
            const int row = waverow + mt * 16 + quad * 4 + s;
            atomicAdd(out + (size_t)row * DV + n, acc[mt][s]);
        }
}

extern "C" void kernel_launch(void* const* d_in, const int* in_sizes, int n_in,
                              void* d_out, int out_size, void* d_ws, size_t ws_size,
                              hipStream_t stream) {
    const float* ls = (const float*)d_in[0];
    const float* x  = (const float*)d_in[1];
    const float* y  = (const float*)d_in[2];
    const float* b  = (const float*)d_in[3];
    float* out = (float*)d_out;

    char* ws = (char*)d_ws;
    bf8* ytbl = (bf8*)ws;                        // 1024*64*16B = 1 MB
    bf8* btbl = (bf8*)(ws + (1 << 20));          // 512*64*16B  = 512 KB

    prep_frags<<<MM / 64, 256, 0, stream>>>(ls, y, b, ytbl, btbl, (float4*)out);
    matern_mfma<<<dim3(NN / ROWS_BLK, JSPLIT), 256, 0, stream>>>(ls, x, ytbl, btbl, out);
}